// Round 3
// baseline (320.420 us; speedup 1.0000x reference)
//
#include <hip/hip_runtime.h>

#define DEVI __device__ __forceinline__

typedef short bf16x8 __attribute__((ext_vector_type(8)));
typedef short bf16x4 __attribute__((ext_vector_type(4)));
typedef float f32x4 __attribute__((ext_vector_type(4)));
typedef unsigned int u32x4 __attribute__((ext_vector_type(4)));
typedef unsigned short u16;

static constexpr int BB = 2, SS = 2048, HH = 1024, HD = 64;
static constexpr int BS = BB * SS;        // 4096 rows
static constexpr int HELEM = SS * HD;     // 131072 elems per head slice
static constexpr float SCALE = 0.03125f;  // 1/sqrt(1024)

DEVI u16 f2bf(float f) {
  union { float f; unsigned u; } v; v.f = f;
  unsigned r = v.u + 0x7fffu + ((v.u >> 16) & 1u);
  return (u16)(r >> 16);
}

// ---------------- f32 -> bf16 converters ----------------
__global__ __launch_bounds__(256) void cvt_inputs(const float* __restrict__ a,
                                                  const float* __restrict__ b,
                                                  u16* __restrict__ oa,
                                                  u16* __restrict__ ob) {
  const int NV = BS * HH / 4;
  int stride = gridDim.x * blockDim.x;
  for (int idx = blockIdx.x * blockDim.x + threadIdx.x; idx < 2 * NV; idx += stride) {
    int which = idx >= NV;
    int e = (which ? idx - NV : idx) * 4;
    const float* src = which ? b : a;
    u16* dst = which ? ob : oa;
    f32x4 v = *(const f32x4*)(src + e);
    unsigned long long pk = (unsigned long long)f2bf(v[0]) |
                            ((unsigned long long)f2bf(v[1]) << 16) |
                            ((unsigned long long)f2bf(v[2]) << 32) |
                            ((unsigned long long)f2bf(v[3]) << 48);
    *(unsigned long long*)(dst + e) = pk;
  }
}

// W [K,N] f32 -> WT [N,K] bf16
__global__ __launch_bounds__(256) void cvt_transpose_w(
    const float* __restrict__ w0, const float* __restrict__ w1,
    const float* __restrict__ w2, const float* __restrict__ w3,
    u16* __restrict__ t0, u16* __restrict__ t1, u16* __restrict__ t2,
    u16* __restrict__ t3) {
  const float* W; u16* T;
  switch (blockIdx.z) {
    case 0: W = w0; T = t0; break;
    case 1: W = w1; T = t1; break;
    case 2: W = w2; T = t2; break;
    default: W = w3; T = t3; break;
  }
  __shared__ float tile[64][65];
  int t = threadIdx.x;
  int bx = blockIdx.x, by = blockIdx.y;
  for (int h = 0; h < 4; ++h) {
    int r = (t >> 4) + h * 16;
    int c0 = (t & 15) * 4;
    f32x4 v = *(const f32x4*)(W + (size_t)(by * 64 + r) * HH + bx * 64 + c0);
    tile[r][c0 + 0] = v[0]; tile[r][c0 + 1] = v[1];
    tile[r][c0 + 2] = v[2]; tile[r][c0 + 3] = v[3];
  }
  __syncthreads();
  for (int h = 0; h < 4; ++h) {
    int nr = (t >> 4) + h * 16;
    int kc0 = (t & 15) * 4;
    unsigned long long pk = 0;
    for (int j = 0; j < 4; ++j)
      pk |= (unsigned long long)f2bf(tile[kc0 + j][nr]) << (16 * j);
    *(unsigned long long*)(T + (size_t)(bx * 64 + nr) * HH + by * 64 + kc0) = pk;
  }
}

// ---------------- 128x128 tile bf16 GEMM, reg-prefetch 2-phase ----------------
template <int OUTF32>
DEVI void gemm_body(const u16* __restrict__ A, const u16* __restrict__ BT,
                    const float* __restrict__ bias, void* __restrict__ Cout,
                    int N, int K, int bm, int bn) {
  __shared__ u16 As[128][72];
  __shared__ u16 Bs[128][72];
  int tid = threadIdx.x, lane = tid & 63, wv = tid >> 6;
  int wr = wv >> 1, wc = wv & 1;
  f32x4 acc[4][4] = {};
  const u16* Ab = A + (size_t)bm * 128 * K;
  const u16* Bb = BT + (size_t)bn * 128 * K;
  u32x4 ra[4], rb[4];
  int sr = tid >> 3, sc = (tid & 7) * 8;

#pragma unroll
  for (int h = 0; h < 4; ++h) {
    ra[h] = *(const u32x4*)(Ab + (size_t)(sr + h * 32) * K + sc);
    rb[h] = *(const u32x4*)(Bb + (size_t)(sr + h * 32) * K + sc);
  }
#pragma unroll
  for (int h = 0; h < 4; ++h) {
    *(u32x4*)(&As[sr + h * 32][sc]) = ra[h];
    *(u32x4*)(&Bs[sr + h * 32][sc]) = rb[h];
  }

  for (int k0 = 64; k0 <= K; k0 += 64) {
    __syncthreads();
    if (k0 < K) {
#pragma unroll
      for (int h = 0; h < 4; ++h) {
        ra[h] = *(const u32x4*)(Ab + (size_t)(sr + h * 32) * K + k0 + sc);
        rb[h] = *(const u32x4*)(Bb + (size_t)(sr + h * 32) * K + k0 + sc);
      }
    }
#pragma unroll
    for (int ks = 0; ks < 2; ++ks) {
      int kk = ks * 32 + (lane >> 4) * 8;
      bf16x8 af[4], bfr[4];
#pragma unroll
      for (int mt = 0; mt < 4; ++mt)
        af[mt] = *(const bf16x8*)(&As[wr * 64 + mt * 16 + (lane & 15)][kk]);
#pragma unroll
      for (int nt = 0; nt < 4; ++nt)
        bfr[nt] = *(const bf16x8*)(&Bs[wc * 64 + nt * 16 + (lane & 15)][kk]);
#pragma unroll
      for (int mt = 0; mt < 4; ++mt)
#pragma unroll
        for (int nt = 0; nt < 4; ++nt)
          acc[mt][nt] = __builtin_amdgcn_mfma_f32_16x16x32_bf16(
              af[mt], bfr[nt], acc[mt][nt], 0, 0, 0);
    }
    __syncthreads();
    if (k0 < K) {
#pragma unroll
      for (int h = 0; h < 4; ++h) {
        *(u32x4*)(&As[sr + h * 32][sc]) = ra[h];
        *(u32x4*)(&Bs[sr + h * 32][sc]) = rb[h];
      }
    }
  }
#pragma unroll
  for (int mt = 0; mt < 4; ++mt)
#pragma unroll
    for (int nt = 0; nt < 4; ++nt) {
      int col = bn * 128 + wc * 64 + nt * 16 + (lane & 15);
      float bv = bias[col];
#pragma unroll
      for (int i = 0; i < 4; ++i) {
        int row = bm * 128 + wr * 64 + mt * 16 + (lane >> 4) * 4 + i;
        float v = acc[mt][nt][i] + bv;
        if (OUTF32)
          ((float*)Cout)[(size_t)row * N + col] = v;
        else
          ((u16*)Cout)[(size_t)row * N + col] = f2bf(v);
      }
    }
}

__global__ __launch_bounds__(256, 3) void qkv_gemm(
    const u16* __restrict__ X, const u16* __restrict__ C,
    const u16* __restrict__ WqT, const u16* __restrict__ WkT,
    const u16* __restrict__ WvT, const float* __restrict__ bq,
    const float* __restrict__ bk, const float* __restrict__ bv,
    u16* __restrict__ Qo, u16* __restrict__ Ko, u16* __restrict__ Vo) {
  const u16 *A, *BT; const float* bias; u16* out;
  if (blockIdx.z == 0)      { A = X; BT = WqT; bias = bq; out = Qo; }
  else if (blockIdx.z == 1) { A = C; BT = WkT; bias = bk; out = Ko; }
  else                      { A = C; BT = WvT; bias = bv; out = Vo; }
  gemm_body<0>(A, BT, bias, out, HH, HH, blockIdx.y, blockIdx.x);
}

__global__ __launch_bounds__(256, 3) void out_gemm(const u16* __restrict__ Att,
                                                   const u16* __restrict__ WoT,
                                                   const float* __restrict__ bo,
                                                   float* __restrict__ out) {
  gemm_body<1>(Att, WoT, bo, out, HH, HH, blockIdx.y, blockIdx.x);
}

// ---------------- per-head permuted V transpose ----------------
// Vt2[d][sigma] = V[kappa(sigma)][d]; within each 32-key chunk,
// kappa: sigma = 32c+8g+j -> 32c + 16*(j>>2) + 4*g + (j&3).
__global__ __launch_bounds__(256) void vtrans(const u16* __restrict__ V,
                                              u16* __restrict__ Vt2) {
  int head = blockIdx.y, kt = blockIdx.x;
  __shared__ u16 tile[64][72];
  int t = threadIdx.x;
  const u16* src = V + (size_t)head * HELEM + kt * 64 * HD;
  for (int h = 0; h < 2; ++h) {
    int r = (t >> 3) + h * 32;
    int c0 = (t & 7) * 8;
    *(u32x4*)(&tile[r][c0]) = *(const u32x4*)(src + r * HD + c0);
  }
  __syncthreads();
  u16* dst = Vt2 + (size_t)head * HELEM;
  for (int h = 0; h < 2; ++h) {
    int d = (t >> 3) + h * 32;
    int s0 = (t & 7) * 8;
    int base32 = s0 & ~31, g = (s0 >> 3) & 3;
    u16 tmp[8];
#pragma unroll
    for (int j = 0; j < 8; ++j)
      tmp[j] = tile[base32 + 16 * (j >> 2) + 4 * g + (j & 3)][d];
    *(u32x4*)(dst + (size_t)d * SS + kt * 64 + s0) = *(u32x4*)tmp;
  }
}

// raw barrier: wait LDS ops only — NEVER drains vmcnt (P-stores stream async)
#define LDS_BARRIER() asm volatile("s_waitcnt lgkmcnt(0)\n\ts_barrier" ::: "memory")

// ---------------- fused two-pass attention ----------------
// 512 threads = 8 waves x 32 q-rows (2 groups of 16; K/V fragments shared
// across groups -> half the LDS traffic). LDS double-buffered K/V, ONE raw
// barrier per kt. Q in regs. No max-tracking. Zero-shuffle P via permuted Vt2.
__global__ __launch_bounds__(512, 2) void attn_fused(
    const u16* __restrict__ Q, const u16* __restrict__ K,
    const u16* __restrict__ Vt2, float* __restrict__ attn_out,
    u16* __restrict__ Att) {
  __shared__ u16 Ks[2][128][72];
  __shared__ u16 Vs[2][64][136];
  int tid = threadIdx.x, lane = tid & 63, wv = tid >> 6;
  int g = lane >> 4, lq = lane & 15;
  int qt = blockIdx.x, bh = blockIdx.y;
  const u16* Qh = Q + (size_t)bh * HELEM + (qt * 256 + wv * 32) * HD;
  const u16* Kh = K + (size_t)bh * HELEM;
  const u16* Vh = Vt2 + (size_t)bh * HELEM;
  float* aout = attn_out + (size_t)(bh * SS + qt * 256 + wv * 32) * SS;

  // Q fragments, both 16-row groups: qf[grp][ks]
  bf16x8 qf[2][2];
#pragma unroll
  for (int grp = 0; grp < 2; ++grp)
#pragma unroll
    for (int ks = 0; ks < 2; ++ks)
      qf[grp][ks] = *(const bf16x8*)(Qh + (grp * 16 + lq) * HD + ks * 32 + g * 8);

  int kr_r = tid >> 3, kr_c = (tid & 7) * 8;   // K stage: rows kr_r, kr_r+64
  int vr_r = tid >> 4, vr_c = (tid & 15) * 8;  // V stage: rows vr_r, vr_r+32
  u32x4 kr0, kr1, vr0, vr1;

  // ================= pass 1: row sums of exp =================
  kr0 = *(const u32x4*)(Kh + (size_t)kr_r * HD + kr_c);
  kr1 = *(const u32x4*)(Kh + (size_t)(kr_r + 64) * HD + kr_c);
  *(u32x4*)(&Ks[0][kr_r][kr_c]) = kr0;
  *(u32x4*)(&Ks[0][kr_r + 64][kr_c]) = kr1;
  LDS_BARRIER();

  float ps0 = 0.0f, ps1 = 0.0f;
  for (int kt = 0; kt < 16; ++kt) {
    int cur = kt & 1;
    if (kt < 15) {
      const u16* kb = Kh + (size_t)(kt + 1) * 128 * HD;
      kr0 = *(const u32x4*)(kb + (size_t)kr_r * HD + kr_c);
      kr1 = *(const u32x4*)(kb + (size_t)(kr_r + 64) * HD + kr_c);
    }
    f32x4 st0[8] = {}, st1[8] = {};
#pragma unroll
    for (int ks = 0; ks < 2; ++ks) {
      int kk = ks * 32 + g * 8;
#pragma unroll
      for (int t = 0; t < 8; ++t) {
        bf16x8 kf = *(const bf16x8*)(&Ks[cur][t * 16 + lq][kk]);
        st0[t] = __builtin_amdgcn_mfma_f32_16x16x32_bf16(kf, qf[0][ks], st0[t], 0, 0, 0);
        st1[t] = __builtin_amdgcn_mfma_f32_16x16x32_bf16(kf, qf[1][ks], st1[t], 0, 0, 0);
      }
    }
#pragma unroll
    for (int t = 0; t < 8; ++t)
#pragma unroll
      for (int i = 0; i < 4; ++i) {
        ps0 += __expf(st0[t][i] * SCALE);
        ps1 += __expf(st1[t][i] * SCALE);
      }
    if (kt < 15) {
      *(u32x4*)(&Ks[cur ^ 1][kr_r][kr_c]) = kr0;
      *(u32x4*)(&Ks[cur ^ 1][kr_r + 64][kr_c]) = kr1;
    }
    LDS_BARRIER();
  }
  ps0 += __shfl_xor(ps0, 16); ps0 += __shfl_xor(ps0, 32);
  ps1 += __shfl_xor(ps1, 16); ps1 += __shfl_xor(ps1, 32);
  float nb0 = -__logf(ps0);  // p = exp(s*SCALE + nb)
  float nb1 = -__logf(ps1);

  // ================= pass 2: write P, accumulate PV =================
  f32x4 accv0[4] = {}, accv1[4] = {};
  kr0 = *(const u32x4*)(Kh + (size_t)kr_r * HD + kr_c);
  kr1 = *(const u32x4*)(Kh + (size_t)(kr_r + 64) * HD + kr_c);
  vr0 = *(const u32x4*)(Vh + (size_t)vr_r * SS + vr_c);
  vr1 = *(const u32x4*)(Vh + (size_t)(vr_r + 32) * SS + vr_c);
  *(u32x4*)(&Ks[0][kr_r][kr_c]) = kr0;
  *(u32x4*)(&Ks[0][kr_r + 64][kr_c]) = kr1;
  *(u32x4*)(&Vs[0][vr_r][vr_c]) = vr0;
  *(u32x4*)(&Vs[0][vr_r + 32][vr_c]) = vr1;
  LDS_BARRIER();

  for (int kt = 0; kt < 16; ++kt) {
    int cur = kt & 1;
    if (kt < 15) {
      const u16* kb = Kh + (size_t)(kt + 1) * 128 * HD;
      const u16* vb = Vh + (size_t)(kt + 1) * 128;
      kr0 = *(const u32x4*)(kb + (size_t)kr_r * HD + kr_c);
      kr1 = *(const u32x4*)(kb + (size_t)(kr_r + 64) * HD + kr_c);
      vr0 = *(const u32x4*)(vb + (size_t)vr_r * SS + vr_c);
      vr1 = *(const u32x4*)(vb + (size_t)(vr_r + 32) * SS + vr_c);
    }
    // QK^T, K-fragment shared across both q-groups
    f32x4 st0[8] = {}, st1[8] = {};
#pragma unroll
    for (int ks = 0; ks < 2; ++ks) {
      int kk = ks * 32 + g * 8;
#pragma unroll
      for (int t = 0; t < 8; ++t) {
        bf16x8 kf = *(const bf16x8*)(&Ks[cur][t * 16 + lq][kk]);
        st0[t] = __builtin_amdgcn_mfma_f32_16x16x32_bf16(kf, qf[0][ks], st0[t], 0, 0, 0);
        st1[t] = __builtin_amdgcn_mfma_f32_16x16x32_bf16(kf, qf[1][ks], st1[t], 0, 0, 0);
      }
    }
    // normalized P: f32 nontemporal store + bf16 pack
    alignas(16) bf16x4 pb0[8], pb1[8];
#pragma unroll
    for (int t = 0; t < 8; ++t) {
      f32x4 p0, p1;
#pragma unroll
      for (int i = 0; i < 4; ++i) {
        p0[i] = __expf(fmaf(st0[t][i], SCALE, nb0));
        p1[i] = __expf(fmaf(st1[t][i], SCALE, nb1));
      }
      __builtin_nontemporal_store(
          p0, (f32x4*)(aout + (size_t)lq * SS + kt * 128 + t * 16 + g * 4));
      __builtin_nontemporal_store(
          p1, (f32x4*)(aout + (size_t)(16 + lq) * SS + kt * 128 + t * 16 + g * 4));
#pragma unroll
      for (int i = 0; i < 4; ++i) { pb0[t][i] = (short)f2bf(p0[i]); pb1[t][i] = (short)f2bf(p1[i]); }
    }
    // PV: V-fragment shared across both q-groups
#pragma unroll
    for (int c = 0; c < 4; ++c) {
      bf16x8 pa0 = *(const bf16x8*)(&pb0[2 * c]);
      bf16x8 pa1 = *(const bf16x8*)(&pb1[2 * c]);
#pragma unroll
      for (int nt = 0; nt < 4; ++nt) {
        bf16x8 vf = *(const bf16x8*)(&Vs[cur][nt * 16 + lq][c * 32 + g * 8]);
        accv0[nt] = __builtin_amdgcn_mfma_f32_16x16x32_bf16(vf, pa0, accv0[nt], 0, 0, 0);
        accv1[nt] = __builtin_amdgcn_mfma_f32_16x16x32_bf16(vf, pa1, accv1[nt], 0, 0, 0);
      }
    }
    if (kt < 15) {
      *(u32x4*)(&Ks[cur ^ 1][kr_r][kr_c]) = kr0;
      *(u32x4*)(&Ks[cur ^ 1][kr_r + 64][kr_c]) = kr1;
      *(u32x4*)(&Vs[cur ^ 1][vr_r][vr_c]) = vr0;
      *(u32x4*)(&Vs[cur ^ 1][vr_r + 32][vr_c]) = vr1;
    }
    LDS_BARRIER();
  }

  // attended -> bf16 workspace (flat layout == reference reshape)
  u16* Ah = Att + (size_t)bh * HELEM + (qt * 256 + wv * 32) * HD;
#pragma unroll
  for (int nt = 0; nt < 4; ++nt) {
    bf16x4 ob0, ob1;
#pragma unroll
    for (int i = 0; i < 4; ++i) { ob0[i] = (short)f2bf(accv0[nt][i]); ob1[i] = (short)f2bf(accv1[nt][i]); }
    *(bf16x4*)(Ah + (size_t)lq * HD + nt * 16 + g * 4) = ob0;
    *(bf16x4*)(Ah + (size_t)(16 + lq) * HD + nt * 16 + g * 4) = ob1;
  }
}

// ---------------- host launch ----------------
extern "C" void kernel_launch(void* const* d_in, const int* in_sizes, int n_in,
                              void* d_out, int out_size, void* d_ws,
                              size_t ws_size, hipStream_t stream) {
  const float* inputs  = (const float*)d_in[0];
  const float* context = (const float*)d_in[1];
  const float* Wq = (const float*)d_in[2];
  const float* bq = (const float*)d_in[3];
  const float* Wk = (const float*)d_in[4];
  const float* bk = (const float*)d_in[5];
  const float* Wv = (const float*)d_in[6];
  const float* bv = (const float*)d_in[7];
  const float* Wo = (const float*)d_in[8];
  const float* bo = (const float*)d_in[9];
  float* out = (float*)d_out;
  float* attn = out + (size_t)BS * HH;

  char* ws = (char*)d_ws;
  u16* Xbf = (u16*)(ws + 0);          // 8 MB
  u16* Cbf = (u16*)(ws + 8388608);    // 8 MB
  u16* WqT = (u16*)(ws + 16777216);   // 2 MB each
  u16* WkT = (u16*)(ws + 18874368);
  u16* WvT = (u16*)(ws + 20971520);
  u16* WoT = (u16*)(ws + 23068672);
  u16* Qb  = (u16*)(ws + 25165824);   // 8 MB
  u16* Kb  = (u16*)(ws + 33554432);   // 8 MB
  u16* Vb  = (u16*)(ws + 41943040);   // 8 MB
  u16* Vtb = Cbf;   // reuse: Cbf dead after qkv_gemm
  u16* Attb = Xbf;  // reuse: Xbf dead after qkv_gemm

  cvt_inputs<<<dim3(2048), dim3(256), 0, stream>>>(inputs, context, Xbf, Cbf);
  cvt_transpose_w<<<dim3(16, 16, 4), dim3(256), 0, stream>>>(
      Wq, Wk, Wv, Wo, WqT, WkT, WvT, WoT);
  qkv_gemm<<<dim3(8, 32, 3), dim3(256), 0, stream>>>(
      Xbf, Cbf, WqT, WkT, WvT, bq, bk, bv, Qb, Kb, Vb);
  vtrans<<<dim3(32, 32), dim3(256), 0, stream>>>(Vb, Vtb);
  attn_fused<<<dim3(8, 32), dim3(512), 0, stream>>>(Qb, Kb, Vtb, attn, Attb);
  out_gemm<<<dim3(8, 32), dim3(256), 0, stream>>>(Attb, WoT, bo, out);
}

// Round 4
// 261.290 us; speedup vs baseline: 1.2263x; 1.2263x over previous
//
#include <hip/hip_runtime.h>

#define DEVI __device__ __forceinline__

typedef short bf16x8 __attribute__((ext_vector_type(8)));
typedef short bf16x4 __attribute__((ext_vector_type(4)));
typedef float f32x4 __attribute__((ext_vector_type(4)));
typedef unsigned int u32x4 __attribute__((ext_vector_type(4)));
typedef unsigned short u16;

static constexpr int BB = 2, SS = 2048, HH = 1024, HD = 64;
static constexpr int BS = BB * SS;        // 4096 rows
static constexpr int HELEM = SS * HD;     // 131072 elems per head slice
static constexpr float SCALE = 0.03125f;  // 1/sqrt(1024)

DEVI u16 f2bf(float f) {
  union { float f; unsigned u; } v; v.f = f;
  unsigned r = v.u + 0x7fffu + ((v.u >> 16) & 1u);
  return (u16)(r >> 16);
}

// async global->LDS, 16B per lane; lds ptr must be wave-uniform
DEVI void gl16(const u16* g, u16* l) {
  __builtin_amdgcn_global_load_lds(
      (const __attribute__((address_space(1))) unsigned int*)g,
      (__attribute__((address_space(3))) unsigned int*)l, 16, 0, 0);
}

// raw barrier: wait LDS ops only — NEVER drains vmcnt (stores stream async)
#define LDS_BARRIER() asm volatile("s_waitcnt lgkmcnt(0)\n\ts_barrier" ::: "memory")

// ---------------- f32 -> bf16 converters ----------------
__global__ __launch_bounds__(256) void cvt_inputs(const float* __restrict__ a,
                                                  const float* __restrict__ b,
                                                  u16* __restrict__ oa,
                                                  u16* __restrict__ ob) {
  const int NV = BS * HH / 4;
  int stride = gridDim.x * blockDim.x;
  for (int idx = blockIdx.x * blockDim.x + threadIdx.x; idx < 2 * NV; idx += stride) {
    int which = idx >= NV;
    int e = (which ? idx - NV : idx) * 4;
    const float* src = which ? b : a;
    u16* dst = which ? ob : oa;
    f32x4 v = *(const f32x4*)(src + e);
    unsigned long long pk = (unsigned long long)f2bf(v[0]) |
                            ((unsigned long long)f2bf(v[1]) << 16) |
                            ((unsigned long long)f2bf(v[2]) << 32) |
                            ((unsigned long long)f2bf(v[3]) << 48);
    *(unsigned long long*)(dst + e) = pk;
  }
}

// W [K,N] f32 -> WT [N,K] bf16
__global__ __launch_bounds__(256) void cvt_transpose_w(
    const float* __restrict__ w0, const float* __restrict__ w1,
    const float* __restrict__ w2, const float* __restrict__ w3,
    u16* __restrict__ t0, u16* __restrict__ t1, u16* __restrict__ t2,
    u16* __restrict__ t3) {
  const float* W; u16* T;
  switch (blockIdx.z) {
    case 0: W = w0; T = t0; break;
    case 1: W = w1; T = t1; break;
    case 2: W = w2; T = t2; break;
    default: W = w3; T = t3; break;
  }
  __shared__ float tile[64][65];
  int t = threadIdx.x;
  int bx = blockIdx.x, by = blockIdx.y;
  for (int h = 0; h < 4; ++h) {
    int r = (t >> 4) + h * 16;
    int c0 = (t & 15) * 4;
    f32x4 v = *(const f32x4*)(W + (size_t)(by * 64 + r) * HH + bx * 64 + c0);
    tile[r][c0 + 0] = v[0]; tile[r][c0 + 1] = v[1];
    tile[r][c0 + 2] = v[2]; tile[r][c0 + 3] = v[3];
  }
  __syncthreads();
  for (int h = 0; h < 4; ++h) {
    int nr = (t >> 4) + h * 16;
    int kc0 = (t & 15) * 4;
    unsigned long long pk = 0;
    for (int j = 0; j < 4; ++j)
      pk |= (unsigned long long)f2bf(tile[kc0 + j][nr]) << (16 * j);
    *(unsigned long long*)(T + (size_t)(bx * 64 + nr) * HH + by * 64 + kc0) = pk;
  }
}

// ------- 128x128 tile bf16 GEMM, global_load_lds staging (m97 pattern) -------
template <int OUTF32>
DEVI void gemm_body(const u16* __restrict__ A, const u16* __restrict__ BT,
                    const float* __restrict__ bias, void* __restrict__ Cout,
                    int N, int K, int bm, int bn) {
  __shared__ u16 As[128 * 64];  // linear: row*64 + col (gload_lds requires)
  __shared__ u16 Bs[128 * 64];
  int tid = threadIdx.x, lane = tid & 63, wv = tid >> 6;
  int wr = wv >> 1, wc = wv & 1;
  int lq = lane & 15, g = lane >> 4;
  f32x4 acc[4][4] = {};
  const u16* Ab = A + (size_t)bm * 128 * K;
  const u16* Bb = BT + (size_t)bn * 128 * K;
  int srow = lane >> 3;           // row within 8-row chunk
  int scol = (lane & 7) * 8;      // elem col within row

  for (int k0 = 0; k0 < K; k0 += 64) {
#pragma unroll
    for (int h = 0; h < 4; ++h) {
      int ch = wv * 4 + h;        // chunk 0..15, wave-uniform
      int row = ch * 8 + srow;
      gl16(Ab + (size_t)row * K + k0 + scol, &As[ch * 512]);
      gl16(Bb + (size_t)row * K + k0 + scol, &Bs[ch * 512]);
    }
    __syncthreads();  // drains vmcnt -> staged data visible
#pragma unroll
    for (int ks = 0; ks < 2; ++ks) {
      int kk = ks * 32 + g * 8;
      bf16x8 af[4], bfr[4];
#pragma unroll
      for (int mt = 0; mt < 4; ++mt)
        af[mt] = *(const bf16x8*)(&As[(wr * 64 + mt * 16 + lq) * 64 + kk]);
#pragma unroll
      for (int nt = 0; nt < 4; ++nt)
        bfr[nt] = *(const bf16x8*)(&Bs[(wc * 64 + nt * 16 + lq) * 64 + kk]);
#pragma unroll
      for (int mt = 0; mt < 4; ++mt)
#pragma unroll
        for (int nt = 0; nt < 4; ++nt)
          acc[mt][nt] = __builtin_amdgcn_mfma_f32_16x16x32_bf16(
              af[mt], bfr[nt], acc[mt][nt], 0, 0, 0);
    }
    __syncthreads();  // all waves done reading before restage
  }
#pragma unroll
  for (int mt = 0; mt < 4; ++mt)
#pragma unroll
    for (int nt = 0; nt < 4; ++nt) {
      int col = bn * 128 + wc * 64 + nt * 16 + lq;
      float bv = bias[col];
#pragma unroll
      for (int i = 0; i < 4; ++i) {
        int row = bm * 128 + wr * 64 + mt * 16 + g * 4 + i;
        float v = acc[mt][nt][i] + bv;
        if (OUTF32)
          ((float*)Cout)[(size_t)row * N + col] = v;
        else
          ((u16*)Cout)[(size_t)row * N + col] = f2bf(v);
      }
    }
}

__global__ __launch_bounds__(256, 3) void qkv_gemm(
    const u16* __restrict__ X, const u16* __restrict__ C,
    const u16* __restrict__ WqT, const u16* __restrict__ WkT,
    const u16* __restrict__ WvT, const float* __restrict__ bq,
    const float* __restrict__ bk, const float* __restrict__ bv,
    u16* __restrict__ Qo, u16* __restrict__ Ko, u16* __restrict__ Vo) {
  const u16 *A, *BT; const float* bias; u16* out;
  if (blockIdx.z == 0)      { A = X; BT = WqT; bias = bq; out = Qo; }
  else if (blockIdx.z == 1) { A = C; BT = WkT; bias = bk; out = Ko; }
  else                      { A = C; BT = WvT; bias = bv; out = Vo; }
  gemm_body<0>(A, BT, bias, out, HH, HH, blockIdx.y, blockIdx.x);
}

__global__ __launch_bounds__(256, 3) void out_gemm(const u16* __restrict__ Att,
                                                   const u16* __restrict__ WoT,
                                                   const float* __restrict__ bo,
                                                   float* __restrict__ out) {
  gemm_body<1>(Att, WoT, bo, out, HH, HH, blockIdx.y, blockIdx.x);
}

// ---------------- per-head permuted V transpose ----------------
// Vt2[d][sigma] = V[kappa(sigma)][d]; within each 32-key chunk,
// kappa: sigma = 32c+8g+j -> 32c + 16*(j>>2) + 4*g + (j&3).
__global__ __launch_bounds__(256) void vtrans(const u16* __restrict__ V,
                                              u16* __restrict__ Vt2) {
  int head = blockIdx.y, kt = blockIdx.x;
  __shared__ u16 tile[64][72];
  int t = threadIdx.x;
  const u16* src = V + (size_t)head * HELEM + kt * 64 * HD;
  for (int h = 0; h < 2; ++h) {
    int r = (t >> 3) + h * 32;
    int c0 = (t & 7) * 8;
    *(u32x4*)(&tile[r][c0]) = *(const u32x4*)(src + r * HD + c0);
  }
  __syncthreads();
  u16* dst = Vt2 + (size_t)head * HELEM;
  for (int h = 0; h < 2; ++h) {
    int d = (t >> 3) + h * 32;
    int s0 = (t & 7) * 8;
    int base32 = s0 & ~31, g = (s0 >> 3) & 3;
    u16 tmp[8];
#pragma unroll
    for (int j = 0; j < 8; ++j)
      tmp[j] = tile[base32 + 16 * (j >> 2) + 4 * g + (j & 3)][d];
    *(u32x4*)(dst + (size_t)d * SS + kt * 64 + s0) = *(u32x4*)tmp;
  }
}

// ---------------- fused two-pass attention ----------------
// 256 threads = 4 waves x 16 q-rows -> 64 q-rows/block; grid (32,32) = 1024
// blocks = 2 blocks/CU (cross-block latency hiding). LDS double-buffered K/V,
// ONE raw LDS barrier per kt (vmcnt never drained -> P stores stream).
// Q in regs. No max-tracking. Zero-shuffle P via permuted Vt2.
__global__ __launch_bounds__(256, 2) void attn_fused(
    const u16* __restrict__ Q, const u16* __restrict__ K,
    const u16* __restrict__ Vt2, float* __restrict__ attn_out,
    u16* __restrict__ Att) {
  __shared__ u16 Ks[2][128][72];
  __shared__ u16 Vs[2][64][136];
  int tid = threadIdx.x, lane = tid & 63, wv = tid >> 6;
  int g = lane >> 4, lq = lane & 15;
  int qt = blockIdx.x, bh = blockIdx.y;
  const u16* Qh = Q + (size_t)bh * HELEM + (qt * 64 + wv * 16) * HD;
  const u16* Kh = K + (size_t)bh * HELEM;
  const u16* Vh = Vt2 + (size_t)bh * HELEM;
  float* aout = attn_out + (size_t)(bh * SS + qt * 64 + wv * 16) * SS;

  // Q fragments: qf[ks][j] = Q[q0+lq][ks*32 + g*8 + j]
  bf16x8 qf0 = *(const bf16x8*)(Qh + lq * HD + g * 8);
  bf16x8 qf1 = *(const bf16x8*)(Qh + lq * HD + 32 + g * 8);

  // staging coords (256 threads)
  int k_r = tid >> 3, k_c = (tid & 7) * 8;    // K: rows k_r + h*32
  int v_r = tid >> 4, v_c = (tid & 15) * 8;   // V: rows v_r + h*16
  u32x4 krg[4], vrg[4];

  // ================= pass 1: row sums of exp =================
#pragma unroll
  for (int h = 0; h < 4; ++h)
    krg[h] = *(const u32x4*)(Kh + (size_t)(h * 32 + k_r) * HD + k_c);
#pragma unroll
  for (int h = 0; h < 4; ++h)
    *(u32x4*)(&Ks[0][h * 32 + k_r][k_c]) = krg[h];
  LDS_BARRIER();

  float ps = 0.0f;
  for (int kt = 0; kt < 16; ++kt) {
    int cur = kt & 1;
    if (kt < 15) {
      const u16* kb = Kh + (size_t)(kt + 1) * 128 * HD;
#pragma unroll
      for (int h = 0; h < 4; ++h)
        krg[h] = *(const u32x4*)(kb + (size_t)(h * 32 + k_r) * HD + k_c);
    }
    f32x4 st[8] = {};
#pragma unroll
    for (int ks = 0; ks < 2; ++ks) {
      bf16x8 qf = ks ? qf1 : qf0;
      int kk = ks * 32 + g * 8;
#pragma unroll
      for (int t = 0; t < 8; ++t) {
        bf16x8 kf = *(const bf16x8*)(&Ks[cur][t * 16 + lq][kk]);
        st[t] = __builtin_amdgcn_mfma_f32_16x16x32_bf16(kf, qf, st[t], 0, 0, 0);
      }
    }
#pragma unroll
    for (int t = 0; t < 8; ++t)
#pragma unroll
      for (int i = 0; i < 4; ++i) ps += __expf(st[t][i] * SCALE);
    if (kt < 15) {
#pragma unroll
      for (int h = 0; h < 4; ++h)
        *(u32x4*)(&Ks[cur ^ 1][h * 32 + k_r][k_c]) = krg[h];
    }
    LDS_BARRIER();
  }
  ps += __shfl_xor(ps, 16);
  ps += __shfl_xor(ps, 32);
  float nb = -__logf(ps);  // p = exp(s*SCALE + nb)

  // ================= pass 2: write P, accumulate PV =================
  f32x4 accv[4] = {};
#pragma unroll
  for (int h = 0; h < 4; ++h) {
    krg[h] = *(const u32x4*)(Kh + (size_t)(h * 32 + k_r) * HD + k_c);
    vrg[h] = *(const u32x4*)(Vh + (size_t)(h * 16 + v_r) * SS + v_c);
  }
#pragma unroll
  for (int h = 0; h < 4; ++h) {
    *(u32x4*)(&Ks[0][h * 32 + k_r][k_c]) = krg[h];
    *(u32x4*)(&Vs[0][h * 16 + v_r][v_c]) = vrg[h];
  }
  LDS_BARRIER();

  for (int kt = 0; kt < 16; ++kt) {
    int cur = kt & 1;
    // prefetch loads FIRST (older than this iter's stores -> in-order vmcnt
    // retirement lets the ds_write wait complete without draining stores)
    if (kt < 15) {
      const u16* kb = Kh + (size_t)(kt + 1) * 128 * HD;
      const u16* vb = Vh + (size_t)(kt + 1) * 128;
#pragma unroll
      for (int h = 0; h < 4; ++h) {
        krg[h] = *(const u32x4*)(kb + (size_t)(h * 32 + k_r) * HD + k_c);
        vrg[h] = *(const u32x4*)(vb + (size_t)(h * 16 + v_r) * SS + v_c);
      }
    }
    f32x4 st[8] = {};
#pragma unroll
    for (int ks = 0; ks < 2; ++ks) {
      bf16x8 qf = ks ? qf1 : qf0;
      int kk = ks * 32 + g * 8;
#pragma unroll
      for (int t = 0; t < 8; ++t) {
        bf16x8 kf = *(const bf16x8*)(&Ks[cur][t * 16 + lq][kk]);
        st[t] = __builtin_amdgcn_mfma_f32_16x16x32_bf16(kf, qf, st[t], 0, 0, 0);
      }
    }
    // normalized P: f32 nontemporal store + bf16 pack
    alignas(16) bf16x4 pb[8];
#pragma unroll
    for (int t = 0; t < 8; ++t) {
      f32x4 p;
#pragma unroll
      for (int i = 0; i < 4; ++i) p[i] = __expf(fmaf(st[t][i], SCALE, nb));
      __builtin_nontemporal_store(
          p, (f32x4*)(aout + (size_t)lq * SS + kt * 128 + t * 16 + g * 4));
#pragma unroll
      for (int i = 0; i < 4; ++i) pb[t][i] = (short)f2bf(p[i]);
    }
    // PV: pa = (pb[2c], pb[2c+1]) is the correct fragment via permuted Vt2
#pragma unroll
    for (int c = 0; c < 4; ++c) {
      bf16x8 pa = *(const bf16x8*)(&pb[2 * c]);
#pragma unroll
      for (int nt = 0; nt < 4; ++nt) {
        bf16x8 vf = *(const bf16x8*)(&Vs[cur][nt * 16 + lq][c * 32 + g * 8]);
        accv[nt] = __builtin_amdgcn_mfma_f32_16x16x32_bf16(vf, pa, accv[nt], 0, 0, 0);
      }
    }
    if (kt < 15) {
#pragma unroll
      for (int h = 0; h < 4; ++h) {
        *(u32x4*)(&Ks[cur ^ 1][h * 32 + k_r][k_c]) = krg[h];
        *(u32x4*)(&Vs[cur ^ 1][h * 16 + v_r][v_c]) = vrg[h];
      }
    }
    LDS_BARRIER();
  }

  // attended -> bf16 workspace (flat layout == reference reshape)
  u16* Ah = Att + (size_t)bh * HELEM + (qt * 64 + wv * 16) * HD;
#pragma unroll
  for (int nt = 0; nt < 4; ++nt) {
    bf16x4 ob;
#pragma unroll
    for (int i = 0; i < 4; ++i) ob[i] = (short)f2bf(accv[nt][i]);
    *(bf16x4*)(Ah + (size_t)lq * HD + nt * 16 + g * 4) = ob;
  }
}

// ---------------- host launch ----------------
extern "C" void kernel_launch(void* const* d_in, const int* in_sizes, int n_in,
                              void* d_out, int out_size, void* d_ws,
                              size_t ws_size, hipStream_t stream) {
  const float* inputs  = (const float*)d_in[0];
  const float* context = (const float*)d_in[1];
  const float* Wq = (const float*)d_in[2];
  const float* bq = (const float*)d_in[3];
  const float* Wk = (const float*)d_in[4];
  const float* bk = (const float*)d_in[5];
  const float* Wv = (const float*)d_in[6];
  const float* bv = (const float*)d_in[7];
  const float* Wo = (const float*)d_in[8];
  const float* bo = (const float*)d_in[9];
  float* out = (float*)d_out;
  float* attn = out + (size_t)BS * HH;

  char* ws = (char*)d_ws;
  u16* Xbf = (u16*)(ws + 0);          // 8 MB
  u16* Cbf = (u16*)(ws + 8388608);    // 8 MB
  u16* WqT = (u16*)(ws + 16777216);   // 2 MB each
  u16* WkT = (u16*)(ws + 18874368);
  u16* WvT = (u16*)(ws + 20971520);
  u16* WoT = (u16*)(ws + 23068672);
  u16* Qb  = (u16*)(ws + 25165824);   // 8 MB
  u16* Kb  = (u16*)(ws + 33554432);   // 8 MB
  u16* Vb  = (u16*)(ws + 41943040);   // 8 MB
  u16* Vtb = Cbf;   // reuse: Cbf dead after qkv_gemm
  u16* Attb = Xbf;  // reuse: Xbf dead after qkv_gemm

  cvt_inputs<<<dim3(2048), dim3(256), 0, stream>>>(inputs, context, Xbf, Cbf);
  cvt_transpose_w<<<dim3(16, 16, 4), dim3(256), 0, stream>>>(
      Wq, Wk, Wv, Wo, WqT, WkT, WvT, WoT);
  qkv_gemm<<<dim3(8, 32, 3), dim3(256), 0, stream>>>(
      Xbf, Cbf, WqT, WkT, WvT, bq, bk, bv, Qb, Kb, Vb);
  vtrans<<<dim3(32, 32), dim3(256), 0, stream>>>(Vb, Vtb);
  attn_fused<<<dim3(32, 32), dim3(256), 0, stream>>>(Qb, Kb, Vtb, attn, Attb);
  out_gemm<<<dim3(8, 32), dim3(256), 0, stream>>>(Attb, WoT, bo, out);
}